// Round 4
// baseline (172.510 us; speedup 1.0000x reference)
//
#include <hip/hip_runtime.h>

#define B_ 8
#define S_ 32
#define C_ 3
#define H_ 256
#define W_ 256
#define HW_ (H_*W_)
#define CHW_ (C_*H_*W_)
#define NT_ 24            // K-tiles of 32
#define TILE_ELEMS 8192   // 256 rows x 32 k

typedef __attribute__((ext_vector_type(8))) short bf16x8;
typedef __attribute__((ext_vector_type(4))) float f32x4;
typedef unsigned int u32;
typedef u32 __attribute__((address_space(3)))* lds_u32p;
typedef const u32 __attribute__((address_space(1)))* glb_u32p;

// truncation-based hi/lo bf16 split of two floats, packed (x low half, y high)
__device__ __forceinline__ void split2(float x, float y, unsigned &hp, unsigned &lp) {
  unsigned ux = __float_as_uint(x), uy = __float_as_uint(y);
  unsigned hx = ux & 0xFFFF0000u, hy = uy & 0xFFFF0000u;
  float lx = x - __uint_as_float(hx);
  float ly = y - __uint_as_float(hy);
  hp = (ux >> 16) | hy;
  lp = (__float_as_uint(lx) >> 16) | (__float_as_uint(ly) & 0xFFFF0000u);
}

__device__ __forceinline__ void gl2lds16(const ushort* g, ushort* l) {
  __builtin_amdgcn_global_load_lds((glb_u32p)g, (lds_u32p)l, 16, 0, 0);
}

// -------- target row reciprocal norms (one wave per 768-elem row) --------
__global__ void ct_ntg(const float* __restrict__ target, float* __restrict__ rntg) {
  int r = (int)((blockIdx.x * (size_t)blockDim.x + threadIdx.x) >> 6);  // 0..2047
  int lane = threadIdx.x & 63;
  const float* base = target + (size_t)(r >> 8) * CHW_ + (size_t)(r & 255) * W_;
  float ss = 0.f;
#pragma unroll
  for (int c = 0; c < C_; ++c)
#pragma unroll
    for (int tt = 0; tt < W_/64; ++tt) {
      float v = base[c*HW_ + tt*64 + lane];
      ss = fmaf(v, v, ss);
    }
#pragma unroll
  for (int off = 32; off; off >>= 1) ss += __shfl_xor(ss, off);
  if (lane == 0) rntg[r] = 1.0f / fmaxf(sqrtf(ss), 1e-12f);
}

// -------- target -> bf16 hi/lo in per-(b,ktile) fragment layout --------
__global__ void ct_bsplit(const float* __restrict__ target,
                          ushort* __restrict__ BhG, ushort* __restrict__ BlG) {
  int bx = blockIdx.x;             // b*24 + kt
  int b  = bx / 24, kt = bx % 24;
  int c  = kt >> 3, w0 = (kt & 7) * 32;
  int t  = threadIdx.x;
  int trow = t >> 3, tw = t & 7;   // 8 threads per row, 4 floats each
  const float* base = target + (size_t)(b*C_ + c) * HW_ + w0 + tw*4;
  ushort* oh = BhG + (size_t)bx * TILE_ELEMS;
  ushort* ol = BlG + (size_t)bx * TILE_ELEMS;
#pragma unroll
  for (int i = 0; i < 8; ++i) {
    int row = trow + 32*i;
    float4 v = *(const float4*)(base + (size_t)row * W_);
    unsigned h0, l0, h1, l1;
    split2(v.x, v.y, h0, l0); split2(v.z, v.w, h1, l1);
    int idx = (row>>4)*512 + (tw>>1)*128 + (row&15)*8 + (tw&1)*4;
    *(uint2*)&oh[idx] = make_uint2(h0, h1);
    *(uint2*)&ol[idx] = make_uint2(l0, l1);
  }
}

// -------- fused corr: MFMA GEMM + A-norms + diagonal reduce + argmax --------
__global__ __launch_bounds__(512)
void ct_corr_mfma(const float* __restrict__ input,
                  const ushort* __restrict__ BhG, const ushort* __restrict__ BlG,
                  const float* __restrict__ rntg_g,
                  int* __restrict__ shift_out) {
  __shared__ ushort AhL[2][TILE_ELEMS], AlL[2][TILE_ELEMS];
  __shared__ ushort BhL[2][TILE_ELEMS], BlL[2][TILE_ELEMS];   // 128 KB total
  __shared__ float ninSq[256], rnin[256], rntg_s[256], corrS[256];
  __shared__ unsigned long long wkey[4];

  const int bs = blockIdx.x;
  const int bG = bs >> 5;
  const int t  = threadIdx.x;
  const int lane = t & 63;
  const int wid  = t >> 6;
  const int wm   = wid >> 2;       // 0..1
  const int wn   = wid & 3;        // 0..3

  const float* Abase = input + (size_t)bs * CHW_;

  if (t < 256) { ninSq[t] = 0.f; corrS[t] = 0.f; rntg_s[t] = rntg_g[bG*256 + t]; }

  f32x4 acc[8][4];
#pragma unroll
  for (int m = 0; m < 8; ++m)
#pragma unroll
    for (int n = 0; n < 4; ++n) acc[m][n] = (f32x4){0.f, 0.f, 0.f, 0.f};

  float4 paE[4], paO[4];
  float ssA[4] = {0.f, 0.f, 0.f, 0.f};

#define ISSUE_A(KT, PA) {                                                     \
    const float* Ab = Abase + (size_t)((KT) >> 3) * HW_ + ((KT) & 7) * 32;    \
    _Pragma("unroll")                                                         \
    for (int p = 0; p < 4; ++p) {                                             \
      int f = p*512 + t;                                                      \
      int row = (f >> 7) * 16 + ((f >> 1) & 15);                              \
      int kk  = ((f >> 5) & 3) * 8 + (f & 1) * 4;                             \
      PA[p] = *(const float4*)(Ab + (size_t)row * W_ + kk);                   \
    } }

  // each wave DMA-loads the B chunk IT will read (cols wn*64..): own-vmcnt covered
#define ISSUE_B(KT, NXP) {                                                    \
    const ushort* gh = BhG + (size_t)(bG*NT_ + (KT)) * TILE_ELEMS + wn*2048;  \
    const ushort* gl = BlG + (size_t)(bG*NT_ + (KT)) * TILE_ELEMS + wn*2048;  \
    _Pragma("unroll")                                                         \
    for (int o = 0; o < 4; ++o)                                               \
      gl2lds16(gh + o*512 + lane*8, &BhL[NXP][wn*2048 + o*512]);              \
    _Pragma("unroll")                                                         \
    for (int o = 0; o < 4; ++o)                                               \
      gl2lds16(gl + o*512 + lane*8, &BlL[NXP][wn*2048 + o*512]);              \
    __builtin_amdgcn_sched_barrier(0); }

#define STASH_A(PA, NXP) {                                                    \
    _Pragma("unroll")                                                         \
    for (int p = 0; p < 4; ++p) {                                             \
      int f = p*512 + t;                                                      \
      int idx = (f>>7)*512 + ((f>>5)&3)*128 + ((f>>1)&15)*8 + (f&1)*4;        \
      float4 va = PA[p];                                                      \
      ssA[p] = fmaf(va.x, va.x, fmaf(va.y, va.y,                              \
               fmaf(va.z, va.z, fmaf(va.w, va.w, ssA[p]))));                  \
      unsigned h0, l0, h1, l1;                                                \
      split2(va.x, va.y, h0, l0); split2(va.z, va.w, h1, l1);                 \
      *(uint2*)&AhL[NXP][idx] = make_uint2(h0, h1);                           \
      *(uint2*)&AlL[NXP][idx] = make_uint2(l0, l1);                           \
    } }

#define MFMA_BODY(CURP) {                                                     \
    bf16x8 bh[4], bl[4];                                                      \
    _Pragma("unroll")                                                         \
    for (int n = 0; n < 4; ++n) {                                             \
      int ct = wn*4 + n;                                                      \
      bh[n] = *(const bf16x8*)&BhL[CURP][ct*512 + lane*8];                    \
      bl[n] = *(const bf16x8*)&BlL[CURP][ct*512 + lane*8];                    \
    }                                                                         \
    __builtin_amdgcn_s_setprio(1);                                            \
    _Pragma("unroll")                                                         \
    for (int m = 0; m < 8; ++m) {                                             \
      int rt = wm*8 + m;                                                      \
      bf16x8 ah = *(const bf16x8*)&AhL[CURP][rt*512 + lane*8];                \
      bf16x8 al = *(const bf16x8*)&AlL[CURP][rt*512 + lane*8];                \
      _Pragma("unroll")                                                       \
      for (int n = 0; n < 4; ++n) {                                           \
        acc[m][n] = __builtin_amdgcn_mfma_f32_16x16x32_bf16(ah, bh[n], acc[m][n], 0, 0, 0); \
        acc[m][n] = __builtin_amdgcn_mfma_f32_16x16x32_bf16(ah, bl[n], acc[m][n], 0, 0, 0); \
        acc[m][n] = __builtin_amdgcn_mfma_f32_16x16x32_bf16(al, bh[n], acc[m][n], 0, 0, 0); \
      }                                                                       \
    }                                                                         \
    __builtin_amdgcn_s_setprio(0); }

#define WAIT_VM4() { asm volatile("s_waitcnt vmcnt(4)" ::: "memory");         \
                     __builtin_amdgcn_sched_barrier(0); }
#define WAIT_VM0() { asm volatile("s_waitcnt vmcnt(0)" ::: "memory");         \
                     __builtin_amdgcn_sched_barrier(0); }
#define BAR() { asm volatile("s_waitcnt lgkmcnt(0)" ::: "memory");            \
                __builtin_amdgcn_sched_barrier(0);                            \
                __builtin_amdgcn_s_barrier();                                 \
                __builtin_amdgcn_sched_barrier(0); }

  // prologue: queue order [A0(4), B0(8), A1(4)]
  ISSUE_A(0, paE);
  __builtin_amdgcn_sched_barrier(0);
  ISSUE_B(0, 0);
  ISSUE_A(1, paO);
  __builtin_amdgcn_sched_barrier(0);
  STASH_A(paE, 0);          // compiler auto-waits vmcnt(12) for paE
  BAR();

  // steady state: at tile kt start, queue = [B(kt)(8), A(kt+1)(4)] -> vmcnt(4)
#define TILE_EVEN(KT, DO_A) {                                                 \
    WAIT_VM4();                                                               \
    ISSUE_B((KT)+1, 1);                                                       \
    MFMA_BODY(0);                                                             \
    STASH_A(paO, 1);                                                          \
    if (DO_A) { ISSUE_A((KT)+2, paE); }                                       \
    BAR(); }
#define TILE_ODD(KT) {                                                        \
    WAIT_VM4();                                                               \
    ISSUE_B((KT)+1, 0);                                                       \
    MFMA_BODY(1);                                                             \
    STASH_A(paE, 0);                                                          \
    ISSUE_A((KT)+2, paO);                                                     \
    BAR(); }

  for (int it = 0; it < 11; ++it) {
    int k0 = 2*it;
    TILE_EVEN(k0, true);
    TILE_ODD(k0 + 1);
  }
  TILE_EVEN(22, false);     // issues B(23), stashes A(23); no more A
  // tile 23: only B(23) outstanding
  WAIT_VM0();
  MFMA_BODY(1);

  // fused A-norms
#pragma unroll
  for (int p = 0; p < 4; ++p) {
    int row = (p*4 + (t >> 7)) * 16 + ((t >> 1) & 15);
    atomicAdd(&ninSq[row], ssA[p]);
  }
  __syncthreads();
  if (t < 256) rnin[t] = 1.0f / fmaxf(sqrtf(ninSq[t]), 1e-12f);
  __syncthreads();

  // normalize + reduce upper diagonals (q = col - row >= 0)
#pragma unroll
  for (int n = 0; n < 4; ++n) {
    int col = wn*64 + n*16 + (lane & 15);
    float rc = rntg_s[col];
#pragma unroll
    for (int m = 0; m < 8; ++m) {
      f32x4 a = acc[m][n];
#pragma unroll
      for (int r = 0; r < 4; ++r) {
        int row = wm*128 + m*16 + (lane >> 4)*4 + r;
        int q = col - row;
        if (q >= 0) atomicAdd(&corrS[q], a[r] * rnin[row] * rc);
      }
    }
  }
  __syncthreads();

  // argmax over p (first max wins) -> shift = q_best
  if (t < 256) {
    int q = 255 - t;
    float v = corrS[q] / (float)(256 - q);
    unsigned u = __float_as_uint(v);
    u = (u & 0x80000000u) ? ~u : (u | 0x80000000u);
    unsigned long long key = ((unsigned long long)u << 32) | (unsigned)q;
#pragma unroll
    for (int off = 32; off; off >>= 1) {
      unsigned long long o = __shfl_xor(key, off);
      if (o > key) key = o;
    }
    if ((t & 63) == 0) wkey[t >> 6] = key;
  }
  __syncthreads();
  if (t == 0) {
    unsigned long long k = wkey[0];
#pragma unroll
    for (int i = 1; i < 4; ++i) if (wkey[i] > k) k = wkey[i];
    shift_out[bs] = (int)(k & 0xFFFFFFFFull);
  }
}

// -------- shifted gather --------
__global__ void ct_gather(const float* __restrict__ input,
                          const int* __restrict__ shift,
                          float* __restrict__ out) {
  size_t idx = (size_t)blockIdx.x * blockDim.x + threadIdx.x;  // float4 units
  int w4 = (int)(idx & 63);
  int h  = (int)((idx >> 6) & 255);
  int sc = (int)(idx >> 14);
  int bs = sc / 3;
  int hh = h + shift[bs];
  float4 v = make_float4(0.f, 0.f, 0.f, 0.f);
  if (hh < H_) v = *(const float4*)(input + ((size_t)sc << 16) + (size_t)hh * W_ + w4*4);
  *(float4*)(out + (idx << 2)) = v;
}

extern "C" void kernel_launch(void* const* d_in, const int* in_sizes, int n_in,
                              void* d_out, int out_size, void* d_ws, size_t ws_size,
                              hipStream_t stream) {
  const float* input  = (const float*)d_in[0];
  const float* target = (const float*)d_in[1];
  float* out = (float*)d_out;

  float* rntg = (float*)d_ws;                       // 2048 f
  int* shift  = (int*)(rntg + 2048);                // 256 i
  ushort* BhG = (ushort*)(shift + 256);             // 8*24*8192 ushort = 3 MB
  ushort* BlG = BhG + (size_t)B_ * NT_ * TILE_ELEMS;

  ct_ntg       <<<512, 256, 0, stream>>>(target, rntg);
  ct_bsplit    <<<B_ * NT_, 256, 0, stream>>>(target, BhG, BlG);
  ct_corr_mfma <<<B_ * S_, 512, 0, stream>>>(input, BhG, BlG, rntg, shift);
  ct_gather    <<<(B_*S_*C_*H_*W_/4) / 256, 256, 0, stream>>>(input, shift, out);
}